// Round 4
// baseline (283.403 us; speedup 1.0000x reference)
//
#include <hip/hip_runtime.h>
#include <hip/hip_bf16.h>

typedef __attribute__((ext_vector_type(4))) float f32x4;
typedef __attribute__((ext_vector_type(8))) short short8;

#define XROWS 8195            // 3 guard rows + 8192
#define XBATCH (XROWS * 1024) // elems per padded batch

__device__ __forceinline__ short f2bf(float f) {
    union { __hip_bfloat16 h; short s; } u;
    u.h = __float2bfloat16(f);
    return u.s;
}

__device__ __forceinline__ void async16(const void* g, void* l) {
    __builtin_amdgcn_global_load_lds(
        (const __attribute__((address_space(1))) unsigned int*)g,
        (__attribute__((address_space(3))) unsigned int*)l, 16, 0, 0);
}

// ---------------------------------------------------------------------------
// Prepass 1: x fp32 [4][8192][1024] -> Xbf bf16 [4][3+8192][1024], guard=0
// ---------------------------------------------------------------------------
__global__ void x_to_bf16(const float* __restrict__ x,
                          __hip_bfloat16* __restrict__ Xbf) {
    size_t idx = (size_t)blockIdx.x * blockDim.x + threadIdx.x;
    if (idx < 1536) {  // zero 4*3*1024 guard elems
        int b = (int)(idx / 384);
        int r = (int)(idx % 384);
        *reinterpret_cast<short8*>(&Xbf[(size_t)b * XBATCH + r * 8]) =
            (short8){0, 0, 0, 0, 0, 0, 0, 0};
    }
    size_t stride = (size_t)gridDim.x * blockDim.x;
    const size_t nvec = (size_t)4 * 8192 * 1024 / 8;
    for (size_t v = idx; v < nvec; v += stride) {
        size_t e = v * 8;
        int b = (int)(e >> 23);
        size_t rem = e & ((1u << 23) - 1);
        f32x4 lo = *reinterpret_cast<const f32x4*>(x + e);
        f32x4 hi = *reinterpret_cast<const f32x4*>(x + e + 4);
        short8 pk;
        pk[0] = f2bf(lo[0]); pk[1] = f2bf(lo[1]); pk[2] = f2bf(lo[2]); pk[3] = f2bf(lo[3]);
        pk[4] = f2bf(hi[0]); pk[5] = f2bf(hi[1]); pk[6] = f2bf(hi[2]); pk[7] = f2bf(hi[3]);
        *reinterpret_cast<short8*>(&Xbf[(size_t)b * XBATCH + 3 * 1024 + rem]) = pk;
    }
}

// ---------------------------------------------------------------------------
// Prepass 2: kernels [4096][1024] fp32 -> Kt [1024][4096] bf16
// ---------------------------------------------------------------------------
__global__ void kconv_transpose(const float* __restrict__ kern,
                                __hip_bfloat16* __restrict__ Kt) {
    __shared__ float tile[32][33];
    int k0 = blockIdx.x << 5;
    int f0 = blockIdx.y << 5;
    int tx = threadIdx.x & 31;
    int ty = threadIdx.x >> 5;
#pragma unroll
    for (int q = 0; q < 4; q++)
        tile[ty + q * 8][tx] = kern[(size_t)(k0 + ty + q * 8) * 1024 + f0 + tx];
    __syncthreads();
#pragma unroll
    for (int q = 0; q < 4; q++)
        Kt[((size_t)(f0 + ty + q * 8) << 12) + k0 + tx] =
            __float2bfloat16(tile[tx][ty + q * 8]);
}

// ---------------------------------------------------------------------------
// Main GEMM, K-slice-32 ring schedule (T2+T3+T4+T5):
//   256x256 tile, 8 waves (2Mx4N), 128 phases of K=32.
//   LDS: 4 slots x 32KB; slot = 256 lines x 128B = A-row 64B | B-row 64B,
//   XOR-swizzled (col ^= (r&7)<<4) within each line -> conflict-free reads;
//   linear DMA dest + inverse-swizzled global source (rule 21).
//   Per phase: 12 ds_read_b128 + stage slice s+3 (4 loads) + 32 MFMA +
//   ONE s_barrier; wait = counted vmcnt(8) every phase (never drains to 0).
//   Tail: wrap-around dummy stages keep vmcnt counts uniform (dead slots).
// ---------------------------------------------------------------------------
__global__ void __launch_bounds__(512, 2)
altconv_gemm4(const __hip_bfloat16* __restrict__ Xbf,  // [4][8195][1024]
              const __hip_bfloat16* __restrict__ Kt,   // [1024][4096]
              const float* __restrict__ biases,        // [4][1024]
              float* __restrict__ out) {               // [32768][1024]
    __shared__ alignas(16) __hip_bfloat16 LS[4 * 16384];  // 128 KiB

    // bijective XCD swizzle (512 blocks % 8 == 0), nt fastest per XCD chunk
    int bid  = blockIdx.x;
    int tid2 = (bid & 7) * 64 + (bid >> 3);
    int mt = tid2 >> 2;           // 0..127
    int nt = tid2 & 3;            // 0..3
    int bm0   = mt << 8;
    int batch = bm0 >> 13;
    int srow0 = bm0 & 8191;
    int bn0   = nt << 8;
    const __hip_bfloat16* xb = Xbf + (size_t)batch * XBATCH;

    int t    = threadIdx.x;
    int lane = t & 63;
    int wid  = t >> 6;            // 0..7
    int wr = wid >> 2, wc = wid & 3;
    int frr = lane & 15, q = lane >> 4;
    int swz = (frr & 7) << 4;

    // fragment read element offsets within a slot (line = 128B = 64 elems)
    int aRd[8], bRd[4];
#pragma unroll
    for (int m = 0; m < 8; m++)
        aRd[m] = (wr * 128 + m * 16 + frr) * 64 + (((q << 4) ^ swz) >> 1);
#pragma unroll
    for (int n = 0; n < 4; n++)
        bRd[n] = (wc * 64 + n * 16 + frr) * 64 + ((((4 + q) << 4) ^ swz) >> 1);

    // staging precompute: linear DMA dest, inverse-swizzled logical source
    int  off[4], ldsE[4];
    bool isA[4];
#pragma unroll
    for (int i = 0; i < 4; i++) {
        int u  = i * 512 + t;          // 16B-chunk index in slot
        int r  = u >> 3;               // line 0..255
        int cp = (u & 7) << 4;         // physical col byte
        int cl = cp ^ ((r & 7) << 4);  // logical col byte (involution)
        ldsE[i] = u * 8;               // elem offset in slot
        isA[i]  = cl < 64;
        off[i]  = isA[i] ? (r * 1024 + (cl >> 1))
                         : (r * 4096 + ((cl - 64) >> 1));
    }

    f32x4 acc[8][4];
#pragma unroll
    for (int m = 0; m < 8; m++)
#pragma unroll
        for (int n = 0; n < 4; n++) acc[m][n] = (f32x4){0.f, 0.f, 0.f, 0.f};

#define STAGEP(SLICE, DSTSLOT) do {                                           \
        int ts_  = (SLICE) & 127;                                             \
        int tap_ = ts_ >> 5;                                                  \
        int c0_  = (ts_ & 31) << 5;                                           \
        const __hip_bfloat16* aS_ =                                           \
            xb + (size_t)(srow0 + 3 - tap_) * 1024 + c0_;                     \
        const __hip_bfloat16* bS_ =                                           \
            Kt + ((size_t)bn0 << 12) + ts_ * 32;                              \
        _Pragma("unroll")                                                     \
        for (int i = 0; i < 4; i++) {                                         \
            const __hip_bfloat16* s_ = (isA[i] ? aS_ : bS_) + off[i];         \
            async16(s_, &LS[(DSTSLOT) * 16384 + ldsE[i]]);                    \
        }                                                                     \
    } while (0)

#define PHASE(SLOT, DSTSLOT, SLICE) do {                                      \
        asm volatile("s_waitcnt vmcnt(8)" ::: "memory");                      \
        __builtin_amdgcn_s_barrier();                                         \
        asm volatile("" ::: "memory");                                        \
        __builtin_amdgcn_sched_barrier(0);                                    \
        short8 af[8], bf4[4];                                                 \
        _Pragma("unroll")                                                     \
        for (int m = 0; m < 8; m++)                                           \
            af[m] = *reinterpret_cast<const short8*>(                         \
                &LS[(SLOT) * 16384 + aRd[m]]);                                \
        _Pragma("unroll")                                                     \
        for (int n = 0; n < 4; n++)                                           \
            bf4[n] = *reinterpret_cast<const short8*>(                        \
                &LS[(SLOT) * 16384 + bRd[n]]);                                \
        STAGEP(SLICE, DSTSLOT);                                               \
        __builtin_amdgcn_s_setprio(1);                                        \
        _Pragma("unroll")                                                     \
        for (int m = 0; m < 8; m++)                                           \
            _Pragma("unroll")                                                 \
            for (int n = 0; n < 4; n++)                                       \
                acc[m][n] = __builtin_amdgcn_mfma_f32_16x16x32_bf16(          \
                    af[m], bf4[n], acc[m][n], 0, 0, 0);                       \
        __builtin_amdgcn_s_setprio(0);                                        \
        __builtin_amdgcn_sched_barrier(0);                                    \
    } while (0)

    // prologue: stage slices 0,1,2 into slots 0,1,2 (12 loads in flight)
    STAGEP(0, 0);
    STAGEP(1, 1);
    STAGEP(2, 2);

    for (int it = 0; it < 32; ++it) {
        int s0 = it << 2;
        PHASE(0, 3, s0 + 3);
        PHASE(1, 0, s0 + 4);
        PHASE(2, 1, s0 + 5);
        PHASE(3, 2, s0 + 6);
    }

    // epilogue: C/D layout col=lane&15, row=(lane>>4)*4+j  [m89]
    int fr   = lane & 15;
    int rowg = (lane >> 4) << 2;
#pragma unroll
    for (int n = 0; n < 4; n++) {
        int gc = bn0 + wc * 64 + n * 16 + fr;
        float bsum = biases[gc] + biases[1024 + gc] + biases[2048 + gc] + biases[3072 + gc];
#pragma unroll
        for (int m = 0; m < 8; m++) {
            size_t gr = (size_t)(bm0 + wr * 128 + m * 16 + rowg);
#pragma unroll
            for (int j = 0; j < 4; j++) {
                out[(gr + j) * 1024 + gc] = acc[m][n][j] + bsum;
            }
        }
    }
#undef STAGEP
#undef PHASE
}

// ---------------------------------------------------------------------------
// Fallback: plain fp32 (no workspace needed), correct but slow
// ---------------------------------------------------------------------------
__global__ void fallback_conv(const float* __restrict__ x, const float* __restrict__ kern,
                              const float* __restrict__ biases, float* __restrict__ out) {
    __shared__ float xs[1024];
    int row = blockIdx.x;
    int f = (blockIdx.y << 8) + threadIdx.x;
    int batch = row >> 13, s = row & 8191;
    const float* xb = x + (((size_t)batch << 13) << 10);
    float acc = 0.f;
    for (int tap = 0; tap < 4; tap++) {
        int ss = s - tap;
        __syncthreads();
        for (int i = threadIdx.x; i < 1024; i += 256)
            xs[i] = (ss >= 0) ? xb[((size_t)ss << 10) + i] : 0.f;
        __syncthreads();
        const float* kp = kern + ((size_t)tap << 20) + f;
        float a = 0.f;
        for (int d = 0; d < 1024; d++) a += xs[d] * kp[(size_t)d << 10];
        acc += a + biases[(tap << 10) + f];
    }
    out[((size_t)row << 10) + f] = acc;
}

extern "C" void kernel_launch(void* const* d_in, const int* in_sizes, int n_in,
                              void* d_out, int out_size, void* d_ws, size_t ws_size,
                              hipStream_t stream) {
    const float* x      = (const float*)d_in[0];
    const float* kern   = (const float*)d_in[1];
    const float* biases = (const float*)d_in[2];
    float* out = (float*)d_out;

    const size_t xbf_bytes = (size_t)4 * XBATCH * sizeof(__hip_bfloat16); // 67.1 MB
    const size_t kt_bytes  = (size_t)4096 * 1024 * sizeof(__hip_bfloat16); // 8.4 MB

    if (ws_size >= xbf_bytes + kt_bytes) {
        __hip_bfloat16* Xbf = (__hip_bfloat16*)d_ws;
        __hip_bfloat16* Kt  = (__hip_bfloat16*)((char*)d_ws + xbf_bytes);
        x_to_bf16<<<2048, 256, 0, stream>>>(x, Xbf);
        kconv_transpose<<<dim3(128, 32), 256, 0, stream>>>(kern, Kt);
        altconv_gemm4<<<512, 512, 0, stream>>>(Xbf, Kt, biases, out);
    } else {
        fallback_conv<<<dim3(32768, 4), 256, 0, stream>>>(x, kern, biases, out);
    }
}

// Round 5
// 276.299 us; speedup vs baseline: 1.0257x; 1.0257x over previous
//
#include <hip/hip_runtime.h>
#include <hip/hip_bf16.h>

typedef __attribute__((ext_vector_type(4))) float f32x4;
typedef __attribute__((ext_vector_type(8))) short short8;

#define XROWS 8195            // 3 guard rows + 8192
#define XBATCH (XROWS * 1024) // elems per padded batch

__device__ __forceinline__ short f2bf(float f) {
    union { __hip_bfloat16 h; short s; } u;
    u.h = __float2bfloat16(f);
    return u.s;
}

__device__ __forceinline__ void async16(const void* g, void* l) {
    __builtin_amdgcn_global_load_lds(
        (const __attribute__((address_space(1))) unsigned int*)g,
        (__attribute__((address_space(3))) unsigned int*)l, 16, 0, 0);
}

// ---------------------------------------------------------------------------
// Prepass 1: x fp32 [4][8192][1024] -> Xbf bf16 [4][3+8192][1024], guard=0
// ---------------------------------------------------------------------------
__global__ void x_to_bf16(const float* __restrict__ x,
                          __hip_bfloat16* __restrict__ Xbf) {
    size_t idx = (size_t)blockIdx.x * blockDim.x + threadIdx.x;
    if (idx < 1536) {  // zero 4*3*1024 guard elems
        int b = (int)(idx / 384);
        int r = (int)(idx % 384);
        *reinterpret_cast<short8*>(&Xbf[(size_t)b * XBATCH + r * 8]) =
            (short8){0, 0, 0, 0, 0, 0, 0, 0};
    }
    size_t stride = (size_t)gridDim.x * blockDim.x;
    const size_t nvec = (size_t)4 * 8192 * 1024 / 8;
    for (size_t v = idx; v < nvec; v += stride) {
        size_t e = v * 8;
        int b = (int)(e >> 23);
        size_t rem = e & ((1u << 23) - 1);
        f32x4 lo = *reinterpret_cast<const f32x4*>(x + e);
        f32x4 hi = *reinterpret_cast<const f32x4*>(x + e + 4);
        short8 pk;
        pk[0] = f2bf(lo[0]); pk[1] = f2bf(lo[1]); pk[2] = f2bf(lo[2]); pk[3] = f2bf(lo[3]);
        pk[4] = f2bf(hi[0]); pk[5] = f2bf(hi[1]); pk[6] = f2bf(hi[2]); pk[7] = f2bf(hi[3]);
        *reinterpret_cast<short8*>(&Xbf[(size_t)b * XBATCH + 3 * 1024 + rem]) = pk;
    }
}

// ---------------------------------------------------------------------------
// Prepass 2: kernels [4096][1024] fp32 -> Kt [1024][4096] bf16
// ---------------------------------------------------------------------------
__global__ void kconv_transpose(const float* __restrict__ kern,
                                __hip_bfloat16* __restrict__ Kt) {
    __shared__ float tile[32][33];
    int k0 = blockIdx.x << 5;
    int f0 = blockIdx.y << 5;
    int tx = threadIdx.x & 31;
    int ty = threadIdx.x >> 5;
#pragma unroll
    for (int q = 0; q < 4; q++)
        tile[ty + q * 8][tx] = kern[(size_t)(k0 + ty + q * 8) * 1024 + f0 + tx];
    __syncthreads();
#pragma unroll
    for (int q = 0; q < 4; q++)
        Kt[((size_t)(f0 + ty + q * 8) << 12) + k0 + tx] =
            __float2bfloat16(tile[tx][ty + q * 8]);
}

// ---------------------------------------------------------------------------
// Main GEMM: 128x128 tile, BK=64, 4 waves (2x2), 2 blocks/CU.
//   LDS: 2-tile dbuf x (A 16KB + B 16KB) = 64KB -> 2 blocks co-resident
//   (stall overlap via co-scheduling, m114). Per K-tile: ONE vmcnt(0) +
//   s_barrier; 16 swizzled ds_read_b128; stage T+1 (8 static loads);
//   32 MFMA under setprio. XOR swizzle (col ^= (r&7)<<4) conflict-free;
//   linear DMA dest + inverse-swizzled global source (rule 21).
// ---------------------------------------------------------------------------
__global__ void __launch_bounds__(256, 2)
altconv_gemm5(const __hip_bfloat16* __restrict__ Xbf,  // [4][8195][1024]
              const __hip_bfloat16* __restrict__ Kt,   // [1024][4096]
              const float* __restrict__ biases,        // [4][1024]
              float* __restrict__ out) {               // [32768][1024]
    __shared__ alignas(16) __hip_bfloat16 LS[2 * 16384];  // 64 KiB

    // bijective XCD swizzle (2048 % 8 == 0); nt fastest within an XCD chunk
    int bid  = blockIdx.x;
    int tid2 = (bid & 7) * 256 + (bid >> 3);
    int mt = tid2 >> 3;           // 0..255
    int nt = tid2 & 7;            // 0..7
    int bm0   = mt << 7;
    int batch = bm0 >> 13;
    int srow0 = bm0 & 8191;
    int bn0   = nt << 7;
    const __hip_bfloat16* xb = Xbf + (size_t)batch * XBATCH;
    const __hip_bfloat16* xA = xb + (size_t)(srow0 + 3) * 1024;
    const __hip_bfloat16* bB = Kt + ((size_t)bn0 << 12);

    int t    = threadIdx.x;
    int lane = t & 63;
    int wid  = t >> 6;            // 0..3
    int wr = wid >> 1, wc = wid & 1;
    int frr = lane & 15, q = lane >> 4;
    int swz = (frr & 7) << 4;     // swizzle byte value

    // fragment read elem offsets (row pitch = 64 elems = 128B)
    int aF[4][2], bF[4][2];
#pragma unroll
    for (int m = 0; m < 4; m++) {
        int r = wr * 64 + m * 16 + frr;
#pragma unroll
        for (int ks = 0; ks < 2; ks++)
            aF[m][ks] = r * 64 + (((ks * 64 + (q << 4)) ^ swz) >> 1);
    }
#pragma unroll
    for (int n = 0; n < 4; n++) {
        int r = wc * 64 + n * 16 + frr;
#pragma unroll
        for (int ks = 0; ks < 2; ks++)
            bF[n][ks] = r * 64 + (((ks * 64 + (q << 4)) ^ swz) >> 1);
    }

    // staging precompute: linear DMA dest elem u*8; inverse-swizzled source
    int aoff[4], boff[4], ldsE[4];
#pragma unroll
    for (int i = 0; i < 4; i++) {
        int u   = i * 256 + t;          // 16B-chunk index within a 16KB slot
        int r   = u >> 3;               // row 0..127
        int clc = (u & 7) ^ (r & 7);    // logical chunk (involution)
        ldsE[i] = u * 8;
        aoff[i] = r * 1024 + clc * 8;
        boff[i] = r * 4096 + clc * 8;
    }

    f32x4 acc[4][4];
#pragma unroll
    for (int m = 0; m < 4; m++)
#pragma unroll
        for (int n = 0; n < 4; n++) acc[m][n] = (f32x4){0.f, 0.f, 0.f, 0.f};

#define STAGE(T) do {                                                         \
        int tap_ = (T) >> 4;                                                  \
        int c0_  = ((T) & 15) << 6;                                           \
        const __hip_bfloat16* aS_ = xA - tap_ * 1024 + c0_;                   \
        const __hip_bfloat16* bS_ = bB + ((T) << 6);                          \
        int dst_ = ((T) & 1) << 14;                                           \
        _Pragma("unroll")                                                     \
        for (int i = 0; i < 4; i++)                                           \
            async16(aS_ + aoff[i], &LS[dst_ + ldsE[i]]);                      \
        _Pragma("unroll")                                                     \
        for (int i = 0; i < 4; i++)                                           \
            async16(bS_ + boff[i], &LS[dst_ + 8192 + ldsE[i]]);               \
    } while (0)

    // prologue: stage tile 0 into buffer 0
    STAGE(0);

    for (int T = 0; T < 64; T++) {
        asm volatile("s_waitcnt vmcnt(0)" ::: "memory");
        __builtin_amdgcn_s_barrier();
        asm volatile("" ::: "memory");
        int base = (T & 1) << 14;

        short8 af0[4], bf0[4], af1[4], bf1[4];
#pragma unroll
        for (int m = 0; m < 4; m++)
            af0[m] = *reinterpret_cast<const short8*>(&LS[base + aF[m][0]]);
#pragma unroll
        for (int n = 0; n < 4; n++)
            bf0[n] = *reinterpret_cast<const short8*>(&LS[base + 8192 + bF[n][0]]);
#pragma unroll
        for (int m = 0; m < 4; m++)
            af1[m] = *reinterpret_cast<const short8*>(&LS[base + aF[m][1]]);
#pragma unroll
        for (int n = 0; n < 4; n++)
            bf1[n] = *reinterpret_cast<const short8*>(&LS[base + 8192 + bF[n][1]]);

        if (T < 63) STAGE(T + 1);

        __builtin_amdgcn_s_setprio(1);
#pragma unroll
        for (int m = 0; m < 4; m++)
#pragma unroll
            for (int n = 0; n < 4; n++)
                acc[m][n] = __builtin_amdgcn_mfma_f32_16x16x32_bf16(
                    af0[m], bf0[n], acc[m][n], 0, 0, 0);
#pragma unroll
        for (int m = 0; m < 4; m++)
#pragma unroll
            for (int n = 0; n < 4; n++)
                acc[m][n] = __builtin_amdgcn_mfma_f32_16x16x32_bf16(
                    af1[m], bf1[n], acc[m][n], 0, 0, 0);
        __builtin_amdgcn_s_setprio(0);
    }

    // epilogue: C/D layout col=lane&15, row=(lane>>4)*4+j  [m89]
    int fr   = lane & 15;
    int rowg = (lane >> 4) << 2;
#pragma unroll
    for (int n = 0; n < 4; n++) {
        int gc = bn0 + wc * 64 + n * 16 + fr;
        float bsum = biases[gc] + biases[1024 + gc] + biases[2048 + gc] + biases[3072 + gc];
#pragma unroll
        for (int m = 0; m < 4; m++) {
            size_t gr = (size_t)(bm0 + wr * 64 + m * 16 + rowg);
#pragma unroll
            for (int j = 0; j < 4; j++) {
                out[(gr + j) * 1024 + gc] = acc[m][n][j] + bsum;
            }
        }
    }
#undef STAGE
}

// ---------------------------------------------------------------------------
// Fallback: plain fp32 (no workspace needed), correct but slow
// ---------------------------------------------------------------------------
__global__ void fallback_conv(const float* __restrict__ x, const float* __restrict__ kern,
                              const float* __restrict__ biases, float* __restrict__ out) {
    __shared__ float xs[1024];
    int row = blockIdx.x;
    int f = (blockIdx.y << 8) + threadIdx.x;
    int batch = row >> 13, s = row & 8191;
    const float* xb = x + (((size_t)batch << 13) << 10);
    float acc = 0.f;
    for (int tap = 0; tap < 4; tap++) {
        int ss = s - tap;
        __syncthreads();
        for (int i = threadIdx.x; i < 1024; i += 256)
            xs[i] = (ss >= 0) ? xb[((size_t)ss << 10) + i] : 0.f;
        __syncthreads();
        const float* kp = kern + ((size_t)tap << 20) + f;
        float a = 0.f;
        for (int d = 0; d < 1024; d++) a += xs[d] * kp[(size_t)d << 10];
        acc += a + biases[(tap << 10) + f];
    }
    out[((size_t)row << 10) + f] = acc;
}

extern "C" void kernel_launch(void* const* d_in, const int* in_sizes, int n_in,
                              void* d_out, int out_size, void* d_ws, size_t ws_size,
                              hipStream_t stream) {
    const float* x      = (const float*)d_in[0];
    const float* kern   = (const float*)d_in[1];
    const float* biases = (const float*)d_in[2];
    float* out = (float*)d_out;

    const size_t xbf_bytes = (size_t)4 * XBATCH * sizeof(__hip_bfloat16); // 67.1 MB
    const size_t kt_bytes  = (size_t)4096 * 1024 * sizeof(__hip_bfloat16); // 8.4 MB

    if (ws_size >= xbf_bytes + kt_bytes) {
        __hip_bfloat16* Xbf = (__hip_bfloat16*)d_ws;
        __hip_bfloat16* Kt  = (__hip_bfloat16*)((char*)d_ws + xbf_bytes);
        x_to_bf16<<<2048, 256, 0, stream>>>(x, Xbf);
        kconv_transpose<<<dim3(128, 32), 256, 0, stream>>>(kern, Kt);
        altconv_gemm5<<<2048, 256, 0, stream>>>(Xbf, Kt, biases, out);
    } else {
        fallback_conv<<<dim3(32768, 4), 256, 0, stream>>>(x, kern, biases, out);
    }
}